// Round 2
// baseline (235.661 us; speedup 1.0000x reference)
//
#include <hip/hip_runtime.h>

#define HD 1024           // hidden dim D
#define D4 (HD/4)         // float4s per row = 256

// Kernel A: column-reduction with direct device-scope atomics.
// Block b handles rows {b, b+G, ...}; thread t owns columns [4t, 4t+4).
// Unrolled 2 rows/iter with independent accumulators for memory-level
// parallelism (2 float4 loads in flight per thread).
__global__ void __launch_bounds__(256) reduce_atomic(
        const float* __restrict__ past,   // [N, HD]
        const float* __restrict__ grad,   // [N]
        float* __restrict__ weighted,     // [HD], pre-zeroed
        int N, int G) {
    const int b = blockIdx.x;
    const int t = threadIdx.x;            // 0..255
    const float4* past4 = (const float4*)past;
    float4 a0 = make_float4(0.f, 0.f, 0.f, 0.f);
    float4 a1 = make_float4(0.f, 0.f, 0.f, 0.f);
    int r = b;
    for (; r + G < N; r += 2 * G) {
        const float g0 = grad[r];                          // uniform broadcast
        const float g1 = grad[r + G];
        const float4 v0 = past4[(size_t)r * D4 + t];       // coalesced 16B/lane
        const float4 v1 = past4[(size_t)(r + G) * D4 + t];
        a0.x += g0 * v0.x; a0.y += g0 * v0.y; a0.z += g0 * v0.z; a0.w += g0 * v0.w;
        a1.x += g1 * v1.x; a1.y += g1 * v1.y; a1.z += g1 * v1.z; a1.w += g1 * v1.w;
    }
    for (; r < N; r += G) {
        const float g = grad[r];
        const float4 v = past4[(size_t)r * D4 + t];
        a0.x += g * v.x; a0.y += g * v.y; a0.z += g * v.z; a0.w += g * v.w;
    }
    a0.x += a1.x; a0.y += a1.y; a0.z += a1.z; a0.w += a1.w;
    // 1024 distinct addresses, ~G adds each — serializes at TCC, ~µs total.
    atomicAdd(&weighted[4 * t + 0], a0.x);
    atomicAdd(&weighted[4 * t + 1], a0.y);
    atomicAdd(&weighted[4 * t + 2], a0.z);
    atomicAdd(&weighted[4 * t + 3], a0.w);
}

// Kernel B: out[i][j] = weighted[i] * cur[j]. Block = output row i.
__global__ void __launch_bounds__(256) outer_kernel(
        const float* __restrict__ weighted,  // [HD]
        const float* __restrict__ cur,       // [HD]
        float* __restrict__ out) {           // [HD, HD]
    const int i = blockIdx.x;
    const int t = threadIdx.x;
    const float w = weighted[i];                       // wave-uniform
    const float4 c = ((const float4*)cur)[t];          // coalesced, L2-hot
    float4 o;
    o.x = w * c.x; o.y = w * c.y; o.z = w * c.z; o.w = w * c.w;
    ((float4*)out)[(size_t)i * D4 + t] = o;            // coalesced 16B/lane
}

extern "C" void kernel_launch(void* const* d_in, const int* in_sizes, int n_in,
                              void* d_out, int out_size, void* d_ws, size_t ws_size,
                              hipStream_t stream) {
    const float* past = (const float*)d_in[0];   // [N, 1024] fp32
    const float* cur  = (const float*)d_in[1];   // [1024] fp32
    const float* grad = (const float*)d_in[2];   // [N] fp32
    float* out = (float*)d_out;                  // [1024, 1024] fp32
    const int N = in_sizes[2];                   // 65536

    float* weighted = (float*)d_ws;              // [1024] floats of scratch

    const int G = 2048;                          // 8 blocks/CU -> 32 waves/CU

    hipMemsetAsync(weighted, 0, HD * sizeof(float), stream);
    reduce_atomic<<<G, 256, 0, stream>>>(past, grad, weighted, N, G);
    outer_kernel<<<HD, 256, 0, stream>>>(weighted, cur, out);
}

// Round 3
// 55.485 us; speedup vs baseline: 4.2473x; 4.2473x over previous
//
#include <hip/hip_runtime.h>

#define HD 1024           // hidden dim D
#define D4 (HD/4)         // float4s per row = 256

// Kernel 1: partial column-reduction. Block b handles rows {b, b+G, ...};
// thread t owns columns [4t, 4t+4). 4-row unroll with independent
// accumulators -> 4 float4 loads in flight per thread (MLP for HBM).
// Writes one coalesced float4 partial per (block, thread). NO atomics.
__global__ void __launch_bounds__(256) partial_reduce(
        const float* __restrict__ past,   // [N, HD]
        const float* __restrict__ grad,   // [N]
        float* __restrict__ partials,     // [G, HD]
        int N, int G) {
    const int b = blockIdx.x;
    const int t = threadIdx.x;            // 0..255
    const float4* past4 = (const float4*)past;
    float4 a0 = make_float4(0.f, 0.f, 0.f, 0.f);
    float4 a1 = make_float4(0.f, 0.f, 0.f, 0.f);
    float4 a2 = make_float4(0.f, 0.f, 0.f, 0.f);
    float4 a3 = make_float4(0.f, 0.f, 0.f, 0.f);
    int r = b;
    for (; r + 3 * G < N; r += 4 * G) {
        const float g0 = grad[r];
        const float g1 = grad[r + G];
        const float g2 = grad[r + 2 * G];
        const float g3 = grad[r + 3 * G];
        const float4 v0 = past4[(size_t)r * D4 + t];
        const float4 v1 = past4[(size_t)(r + G) * D4 + t];
        const float4 v2 = past4[(size_t)(r + 2 * G) * D4 + t];
        const float4 v3 = past4[(size_t)(r + 3 * G) * D4 + t];
        a0.x += g0 * v0.x; a0.y += g0 * v0.y; a0.z += g0 * v0.z; a0.w += g0 * v0.w;
        a1.x += g1 * v1.x; a1.y += g1 * v1.y; a1.z += g1 * v1.z; a1.w += g1 * v1.w;
        a2.x += g2 * v2.x; a2.y += g2 * v2.y; a2.z += g2 * v2.z; a2.w += g2 * v2.w;
        a3.x += g3 * v3.x; a3.y += g3 * v3.y; a3.z += g3 * v3.z; a3.w += g3 * v3.w;
    }
    for (; r < N; r += G) {
        const float g = grad[r];
        const float4 v = past4[(size_t)r * D4 + t];
        a0.x += g * v.x; a0.y += g * v.y; a0.z += g * v.z; a0.w += g * v.w;
    }
    a0.x += a1.x + a2.x + a3.x;
    a0.y += a1.y + a2.y + a3.y;
    a0.z += a1.z + a2.z + a3.z;
    a0.w += a1.w + a2.w + a3.w;
    ((float4*)partials)[(size_t)b * D4 + t] = a0;      // coalesced 16B/lane
}

// Kernel 2: fused final-reduce + outer product. Block handles 4 output rows
// R..R+3. Lane t reduces partials column R+(t&3) over g = (t>>2) step 64,
// then __shfl_xor over lane bits 2..5 + tiny LDS combine -> weighted[R..R+3],
// then writes 4 coalesced float4 rows of out.
__global__ void __launch_bounds__(256) finish_outer(
        const float* __restrict__ partials,  // [G, HD]
        const float* __restrict__ cur,       // [HD]
        float* __restrict__ out,             // [HD, HD]
        int G) {
    __shared__ float lds[16];
    __shared__ float wrow[4];
    const int t = threadIdx.x;               // 0..255
    const int R = blockIdx.x * 4;            // first output row of this block
    const int c = R + (t & 3);               // partials column this lane sums
    float acc = 0.f;
    for (int g = (t >> 2); g < G; g += 64)
        acc += partials[(size_t)g * HD + c];
    // reduce across lanes with equal (lane&3): flip lane bits 2..5
    acc += __shfl_xor(acc, 4);
    acc += __shfl_xor(acc, 8);
    acc += __shfl_xor(acc, 16);
    acc += __shfl_xor(acc, 32);
    const int lane = t & 63, wave = t >> 6;
    if (lane < 4) lds[wave * 4 + lane] = acc;
    __syncthreads();
    if (t < 4) wrow[t] = lds[t] + lds[4 + t] + lds[8 + t] + lds[12 + t];
    __syncthreads();
    const float4 cv = ((const float4*)cur)[t];          // coalesced, L2-hot
    #pragma unroll
    for (int j = 0; j < 4; ++j) {
        const float w = wrow[j];
        float4 o;
        o.x = w * cv.x; o.y = w * cv.y; o.z = w * cv.z; o.w = w * cv.w;
        ((float4*)out)[(size_t)(R + j) * D4 + t] = o;   // coalesced 16B/lane
    }
}

extern "C" void kernel_launch(void* const* d_in, const int* in_sizes, int n_in,
                              void* d_out, int out_size, void* d_ws, size_t ws_size,
                              hipStream_t stream) {
    const float* past = (const float*)d_in[0];   // [N, 1024] fp32
    const float* cur  = (const float*)d_in[1];   // [1024] fp32
    const float* grad = (const float*)d_in[2];   // [N] fp32
    float* out = (float*)d_out;                  // [1024, 1024] fp32
    const int N = in_sizes[2];                   // 65536

    float* partials = (float*)d_ws;              // [G, 1024] floats

    int G = 1024;                                // 4 blocks/CU, 16 waves/CU
    const size_t avail_floats = ws_size / sizeof(float);
    if ((size_t)G * HD > avail_floats) {
        G = (int)(avail_floats / HD);
        if (G < 1) G = 1;
    }

    partial_reduce<<<G, 256, 0, stream>>>(past, grad, partials, N, G);
    finish_outer<<<HD / 4, 256, 0, stream>>>(partials, cur, out, G);
}